// Round 6
// baseline (424.859 us; speedup 1.0000x reference)
//
#include <hip/hip_runtime.h>
#include <stdint.h>

// R6 = R5 resubmitted verbatim. R5 bench died with "container failed twice"
// (no pytest/absmax/counters -> no kernel-attributable signal). Same
// signature as R3, which resolved as infra flake when R4 resubmitted
// verbatim and passed. Kernel audit found no hang/fault mechanism: uniform
// barriers, satisfiable waits, in-bounds addressing, finite loops.
// If this fails twice-in-a-row again, R7 bisects by reverting to exact R4.
//
// R5: GEMM inner compute switched 16x16x64 -> 32x32x32 i8 MFMA.
// Rationale: i8 16x16 ubench ceiling 3944 TOPS vs 32x32 4404 (+12%), and
// halved MFMA issue-slot pressure. Staging, XOR swizzle, 4-phase ledger,
// lgkm/vmcnt counts all byte-identical to R4 (reads/phase still 8/4 b128).
// prep/finalize/quant byte-identical to R0-R4.

#define QMAXF 127.0f

constexpr int Mdim = 8192;
constexpr int Kdim = 4096;
constexpr int Ndim = 4096;
constexpr int PREP_BLOCKS = 2048;

using i32x4 = __attribute__((ext_vector_type(4))) int;
using i32x16 = __attribute__((ext_vector_type(16))) int;

__device__ __forceinline__ void async_copy16(const void* g, void* l) {
    __builtin_amdgcn_global_load_lds(
        (const __attribute__((address_space(1))) void*)g,
        (__attribute__((address_space(3))) void*)l,
        16, 0, 0);
}

// ---------------------------------------------------------------------------
// Pass 1: per-block |x| maxima (plain stores, NO atomics) + w int32->int8.
// ---------------------------------------------------------------------------
__global__ void prep_kernel(const float* __restrict__ x,
                            const int* __restrict__ w32,
                            float* __restrict__ blockmax,
                            int8_t* __restrict__ w8) {
    float m = 0.f;
    const float4* x4 = (const float4*)x;
    const int n4x = Mdim * Kdim / 4;
    for (int i = blockIdx.x * blockDim.x + threadIdx.x; i < n4x;
         i += gridDim.x * blockDim.x) {
        float4 v = x4[i];
        m = fmaxf(fmaxf(fabsf(v.x), fabsf(v.y)),
                  fmaxf(m, fmaxf(fabsf(v.z), fabsf(v.w))));
    }
#pragma unroll
    for (int off = 32; off > 0; off >>= 1)
        m = fmaxf(m, __shfl_down(m, off, 64));
    __shared__ float red[4];
    if ((threadIdx.x & 63) == 0) red[threadIdx.x >> 6] = m;
    __syncthreads();
    if (threadIdx.x == 0)
        blockmax[blockIdx.x] =
            fmaxf(fmaxf(red[0], red[1]), fmaxf(red[2], red[3]));

    // fused: narrow w (independent of the reduction above)
    const int4* in4 = (const int4*)w32;
    char4* out4 = (char4*)w8;
    const int n4w = Ndim * Kdim / 4;
    for (int i = blockIdx.x * blockDim.x + threadIdx.x; i < n4w;
         i += gridDim.x * blockDim.x) {
        int4 v = in4[i];
        char4 c;
        c.x = (signed char)v.x;
        c.y = (signed char)v.y;
        c.z = (signed char)v.z;
        c.w = (signed char)v.w;
        out4[i] = c;
    }
}

// Pass 2: reduce 2048 block maxima -> s_x = max/127 (one block, ~3 us)
__global__ void finalize_kernel(const float* __restrict__ blockmax,
                                float* __restrict__ sx) {
    float m = 0.f;
    for (int i = threadIdx.x; i < PREP_BLOCKS; i += 256)
        m = fmaxf(m, blockmax[i]);
#pragma unroll
    for (int off = 32; off > 0; off >>= 1)
        m = fmaxf(m, __shfl_down(m, off, 64));
    __shared__ float red[4];
    if ((threadIdx.x & 63) == 0) red[threadIdx.x >> 6] = m;
    __syncthreads();
    if (threadIdx.x == 0)
        *sx = fmaxf(fmaxf(red[0], red[1]), fmaxf(red[2], red[3])) / QMAXF;
}

// Pass 3: quantize x -> int8 with the (now known) scalar scale
__global__ void quant_x_kernel(const float* __restrict__ x,
                               const float* __restrict__ sxp,
                               int8_t* __restrict__ xq, int n4) {
    const float s = *sxp;
    const float4* x4 = (const float4*)x;
    char4* q4 = (char4*)xq;
    for (int i = blockIdx.x * blockDim.x + threadIdx.x; i < n4;
         i += gridDim.x * blockDim.x) {
        float4 v = x4[i];
        char4 q;
        q.x = (signed char)(int)fminf(QMAXF, fmaxf(-QMAXF, rintf(v.x / s)));
        q.y = (signed char)(int)fminf(QMAXF, fmaxf(-QMAXF, rintf(v.y / s)));
        q.z = (signed char)(int)fminf(QMAXF, fmaxf(-QMAXF, rintf(v.z / s)));
        q.w = (signed char)(int)fminf(QMAXF, fmaxf(-QMAXF, rintf(v.w / s)));
        q4[i] = q;
    }
}

// ---------------------------------------------------------------------------
// int8 GEMM: C[M,N] = Xq[M,K] . Wq[N,K]^T
// 256x256 tile, BK=128 bytes, 8 waves (2Mx4N), read-ahead pipelined schedule
// (R4 ledger, unchanged), inner compute = mfma_i32_32x32x32_i8.
//
// Fragment layouts (derived as the direct analog of the verified 16x16x64
// usage; C/D mapping is the guide's HW-verified 32x32 one):
//   A operand: lane l holds row (l&31) of the 32-row M-block, K bytes
//              [16*(l>>5), 16*(l>>5)+16) of the 32-B K-chunk  -> 1 b128.
//   B operand: lane l holds col (l&31) (= Wq row), same K split.
//   C/D:       col = lane&31, row = (reg&3) + 8*(reg>>2) + 4*(lane>>5).
// Per wave per K-tile(128B): A-frags 2mh x 2m x 4kc = 16 b128, B-frags
// 2nh x 4kc = 8 b128 (counts identical to R4 -> same lgkm ledger), 32 MFMA
// (vs 64 before; pipe ceiling 4404 vs 3944 TOPS).
// Bank conflicts: slot index (kc*2+hi)^(row&7) distinct across each 8-row
// group -> 2 lanes/bank = free.
//
// Schedule per tile T (buf b=T&1, other b') - byte-identical to R4:
//   P1: read b1(T)[4];  lgkm(4);  MFMA(mh0,nh0); stage B1(T+1); vm(6); BAR
//   P2: read a1(T)[8];  lgkm(8);  MFMA(mh0,nh1); stage A1(T+1); vm(6); BAR
//   P3: read a0(T+1)[8];lgkm(8);  MFMA(mh1,nh0); stage A0(T+2); vm(6); BAR
//   P4: read b0(T+1)[4];no lgkm;  MFMA(mh1,nh1); stage B0(T+2); vm(6); BAR
// (safety ledger as R4: every stage's region drained >=1 barrier earlier;
//  every read's data staged 3 phases / vmcnt(6) ahead; tail clamps kt-2.)
// ---------------------------------------------------------------------------
#define BM 256
#define BN 256
#define BKB 128
#define NKT (Kdim / BKB)  // 32

#define BARF()                              \
    do {                                    \
        __builtin_amdgcn_s_barrier();       \
        __builtin_amdgcn_sched_barrier(0);  \
    } while (0)

#define WAITLGKM(N)                                                  \
    do {                                                             \
        asm volatile("s_waitcnt lgkmcnt(" #N ")" ::: "memory");      \
        __builtin_amdgcn_sched_barrier(0);                           \
    } while (0)

#define WAITVM(N) asm volatile("s_waitcnt vmcnt(" #N ")" ::: "memory")

__global__ __launch_bounds__(512, 2) void gemm_i8_kernel(
    const int8_t* __restrict__ Xq, const int8_t* __restrict__ Wq,
    const float* __restrict__ sxp, const float* __restrict__ s_w,
    const float* __restrict__ bias, float* __restrict__ Y) {
    __shared__ int8_t lds[131072];  // [buf][A 32K | B 32K]

    const int t = threadIdx.x;
    const int w = t >> 6;
    const int l = t & 63;
    const int lane31 = l & 31;
    const int hi = l >> 5;        // K-half selector for 32x32 operands
    const int swz7 = l & 7;       // row&7 for both A and B reads

    // XCD-aware bijective swizzle: 512 blocks, 8 XCDs, 64 contiguous per XCD
    const int flat = blockIdx.y * gridDim.x + blockIdx.x;
    const int swzb = (flat & 7) * 64 + (flat >> 3);
    const int bn = (swzb & 15) * BN;
    const int bm = (swzb >> 4) * BM;

    // --- staging source (per-thread, pre-swizzled global address) ---------
    // half-tile = 128 rows x 128 B = 1024 chunks of 16 B; thread t owns rows
    // r0 = t>>3 and r0+64, slot p = t&7 holding global chunk p ^ (r&7).
    const int r0 = t >> 3;
    const int cOff = ((t & 7) ^ (r0 & 7)) * 16;
    const int8_t* aS = Xq + (size_t)(bm + r0) * Kdim + cOff;
    const int8_t* bS = Wq + (size_t)(bn + r0) * Kdim + cOff;
    const int wb = w * 1024;  // wave-uniform LDS offset (HW adds lane*16)

    // --- fragment-read bases (8 waves tile the 256x256 output 2Mx4N) ------
    // wave rows (w>>2)*64 .. +63 within each 128-row half; cols (w&3)*32.
    const int aRowOff = ((w >> 2) * 64 + lane31) * BKB;
    const int bRowOff = ((w & 3) * 32 + lane31) * BKB;
    // swizzled 16-B slot offsets for the 4 K-chunks of a 128-B row
    int kSl[4];
#pragma unroll
    for (int kc = 0; kc < 4; ++kc) kSl[kc] = (((kc << 1) | hi) ^ swz7) * 16;

    i32x16 acc[2][2][2] = {};        // [mh][nh][m]
    i32x4 a0[2][4], a1[2][4];        // [m][kc]
    i32x4 b0[4], b1[4];              // [kc]

    int8_t* const ldsA_ = lds;
    int8_t* const ldsB_ = lds + 32768;

#define STAGE(SRC, LBASE, h, kt)                                              \
    do {                                                                      \
        const int _kt = (kt) < NKT ? (kt) : (NKT - 2 + ((kt) & 1));           \
        const int8_t* _s =                                                    \
            (SRC) + (size_t)(h) * 128 * Kdim + (size_t)_kt * BKB;             \
        int8_t* _d = (LBASE) + (_kt & 1) * 65536 + (h) * 16384 + wb;          \
        async_copy16(_s, _d);                                                 \
        async_copy16(_s + (size_t)64 * Kdim, _d + 8192);                      \
    } while (0)

// 8 ds_read_b128: 2 M-blocks x 4 K-chunks of one A half-tile
#define LDFRAG_A(dst, BOFF, mh)                                               \
    do {                                                                      \
        const int8_t* _p = lds + (BOFF) + (mh) * 16384 + aRowOff;             \
        _Pragma("unroll") for (int m = 0; m < 2; ++m)                         \
            _Pragma("unroll") for (int kc = 0; kc < 4; ++kc)                  \
                dst[m][kc] = *(const i32x4*)(_p + m * 4096 + kSl[kc]);        \
    } while (0)

// 4 ds_read_b128: 1 N-block x 4 K-chunks of one B half-tile
#define LDFRAG_B(dst, BOFF, nh)                                               \
    do {                                                                      \
        const int8_t* _p = lds + 32768 + (BOFF) + (nh) * 16384 + bRowOff;     \
        _Pragma("unroll") for (int kc = 0; kc < 4; ++kc)                      \
            dst[kc] = *(const i32x4*)(_p + kSl[kc]);                          \
    } while (0)

// 8 MFMA: 2 M-blocks x 4 K-chunks into acc[mh][nh][m]
#define MFMAQ(mh, nh, A, B)                                                   \
    do {                                                                      \
        __builtin_amdgcn_s_setprio(1);                                        \
        _Pragma("unroll") for (int kc = 0; kc < 4; ++kc)                      \
            _Pragma("unroll") for (int m = 0; m < 2; ++m)                     \
                acc[mh][nh][m] = __builtin_amdgcn_mfma_i32_32x32x32_i8(       \
                    (A)[m][kc], (B)[kc], acc[mh][nh][m], 0, 0, 0);            \
        __builtin_amdgcn_s_setprio(0);                                        \
    } while (0)

#define GROUP(T, BOFF, OBOFF)                                                 \
    do {                                                                      \
        /* P1: (mh0,nh0) on a0,b0 */                                          \
        LDFRAG_B(b1, BOFF, 1);                                                \
        WAITLGKM(4);                                                          \
        MFMAQ(0, 0, a0, b0);                                                  \
        STAGE(bS, ldsB_, 1, (T) + 1);                                         \
        WAITVM(6);                                                            \
        BARF();                                                               \
        /* P2: (mh0,nh1) on a0,b1 -- a0 dies here */                          \
        LDFRAG_A(a1, BOFF, 1);                                                \
        WAITLGKM(8);                                                          \
        MFMAQ(0, 1, a0, b1);                                                  \
        STAGE(aS, ldsA_, 1, (T) + 1);                                         \
        WAITVM(6);                                                            \
        BARF();                                                               \
        /* P3: (mh1,nh0) on a1,b0 -- b0 dies here; a0 reloaded at head */     \
        LDFRAG_A(a0, OBOFF, 0);                                               \
        WAITLGKM(8);                                                          \
        MFMAQ(1, 0, a1, b0);                                                  \
        STAGE(aS, ldsA_, 0, (T) + 2);                                         \
        WAITVM(6);                                                            \
        BARF();                                                               \
        /* P4: (mh1,nh1) on a1,b1 -- operands drained P2/P3: no lgkm wait */  \
        LDFRAG_B(b0, OBOFF, 0);                                               \
        MFMAQ(1, 1, a1, b1);                                                  \
        STAGE(bS, ldsB_, 0, (T) + 2);                                         \
        WAITVM(6);                                                            \
        BARF();                                                               \
    } while (0)

    // prologue: tile0 {A0,B0,B1} must land; {A1(0),A0(1),B0(1)} may fly (=3
    // pairs, the steady vmcnt(6) invariant). Then prefetch a0/b0 frags.
    STAGE(aS, ldsA_, 0, 0);
    STAGE(bS, ldsB_, 0, 0);
    STAGE(bS, ldsB_, 1, 0);
    STAGE(aS, ldsA_, 1, 0);
    STAGE(aS, ldsA_, 0, 1);
    STAGE(bS, ldsB_, 0, 1);
    WAITVM(6);
    BARF();
    LDFRAG_A(a0, 0, 0);
    LDFRAG_B(b0, 0, 0);

    for (int t2 = 0; t2 < NKT; t2 += 2) {
        GROUP(t2, 0, 65536);
        GROUP(t2 + 1, 65536, 0);
    }

    // epilogue: 32x32 C/D layout col=lane&31, row=(reg&3)+8*(reg>>2)+4*hi
    const float sx = *sxp;
    const int wmE = (w >> 2) * 64;
    const int wnE = (w & 3) * 32;
#pragma unroll
    for (int nh = 0; nh < 2; ++nh) {
        const int col = bn + nh * 128 + wnE + lane31;
        const float sc = sx * s_w[col];
        const float bs = bias[col];
#pragma unroll
        for (int mh = 0; mh < 2; ++mh) {
#pragma unroll
            for (int m = 0; m < 2; ++m) {
                const int rowBase = bm + mh * 128 + wmE + m * 32 + hi * 4;
#pragma unroll
                for (int q = 0; q < 4; ++q) {
                    float* yp = Y + (size_t)(rowBase + 8 * q) * Ndim + col;
#pragma unroll
                    for (int rr = 0; rr < 4; ++rr)
                        yp[(size_t)rr * Ndim] =
                            (float)acc[mh][nh][m][q * 4 + rr] * sc + bs;
                }
            }
        }
    }
}

extern "C" void kernel_launch(void* const* d_in, const int* in_sizes, int n_in,
                              void* d_out, int out_size, void* d_ws,
                              size_t ws_size, hipStream_t stream) {
    const float* x = (const float*)d_in[0];
    const int* w_q = (const int*)d_in[1];  // integer inputs arrive as int32
    const float* s_w = (const float*)d_in[2];
    const float* bias = (const float*)d_in[3];
    float* y = (float*)d_out;

    float* sx = (float*)d_ws;                       // [0]      scalar scale
    float* blockmax = (float*)((char*)d_ws + 256);  // [256]    2048 floats
    int8_t* xq = (int8_t*)d_ws + 16384;
    int8_t* wq8 = (int8_t*)d_ws + 16384 + (size_t)Mdim * Kdim;

    prep_kernel<<<PREP_BLOCKS, 256, 0, stream>>>(x, w_q, blockmax, wq8);
    finalize_kernel<<<1, 256, 0, stream>>>(blockmax, sx);
    quant_x_kernel<<<PREP_BLOCKS, 256, 0, stream>>>(x, sx, xq,
                                                    Mdim * Kdim / 4);

    dim3 grid(Ndim / BN, Mdim / BM);
    gemm_i8_kernel<<<grid, 512, 0, stream>>>(xq, wq8, sx, s_w, bias, y);
}